// Round 3
// baseline (599.387 us; speedup 1.0000x reference)
//
#include <hip/hip_runtime.h>
#include <stdint.h>

#define O_DIM 2048
#define I_DIM 4096
#define BS_TOK 8192   // 4*2048 tokens
#define KCB 256
#define PQD 8

typedef __attribute__((ext_vector_type(8))) __bf16 bf16x8;
typedef __attribute__((ext_vector_type(4))) float f32x4;

static __device__ __forceinline__ unsigned short f32_to_bf16(float f) {
    unsigned int u = __float_as_uint(f);
    u += 0x7fffu + ((u >> 16) & 1u);   // round-to-nearest-even
    return (unsigned short)(u >> 16);
}

static __device__ __forceinline__ unsigned int pack2(unsigned short lo, unsigned short hi) {
    return (unsigned int)lo | ((unsigned int)hi << 16);
}

// ---------------- 1. fused rowscale + fp32-filter assignment, cheap exact fallback ----------------
// e(c) = -2*(w.c) + s*||c||^2 has the same argmin as ||w/s - c||^2 (scale by s>0).
// With ||c||^2 in fp64 and snc single-rounded, |e32 - exact| <= ~2.5e-5, so a
// fp32 margin > 5e-5 certifies the winner. Flag at TAU=1.2e-4; flagged groups
// rerun the FP32 loop and fp64-evaluate only candidates within CUT=2.5e-4 of
// best (expected 1-3), ascending c (np.argmin first-min tiebreak). The fp64
// formula is identical to the round-1 kernel that verified at absmax 4.0.
#define TAU 1.2e-4f
#define CUT 2.5e-4f

__global__ __launch_bounds__(256) void fused_assign_kernel(const float* __restrict__ weight,
                                                           const float* __restrict__ codebook,
                                                           unsigned short* __restrict__ wq) {
    __shared__ __align__(16) float cb[KCB * PQD];   // 8 KB
    __shared__ float sn[KCB];                       // 1 KB  (fl( s * ||c||^2_fp64 ))
    __shared__ float red[4];

    const int o = blockIdx.x;
    const int t = threadIdx.x;

    // --- load my 16 weights (2 groups) ---
    const float* wp = weight + (size_t)o * I_DIM + t * 16;
    float w[16];
    {
        float4 a = *(const float4*)(wp);
        float4 b = *(const float4*)(wp + 4);
        float4 c = *(const float4*)(wp + 8);
        float4 d = *(const float4*)(wp + 12);
        w[0]=a.x; w[1]=a.y; w[2]=a.z; w[3]=a.w;
        w[4]=b.x; w[5]=b.y; w[6]=b.z; w[7]=b.w;
        w[8]=c.x; w[9]=c.y; w[10]=c.z; w[11]=c.w;
        w[12]=d.x; w[13]=d.y; w[14]=d.z; w[15]=d.w;
    }

    // --- my codeword -> LDS; exact norm in fp64 (kept in reg) ---
    float4 c0 = *(const float4*)(codebook + t * PQD);
    float4 c1 = *(const float4*)(codebook + t * PQD + 4);
    *(float4*)&cb[t * PQD]     = c0;
    *(float4*)&cb[t * PQD + 4] = c1;
    double n2d = 0.0;
    n2d = fma((double)c0.x, (double)c0.x, n2d); n2d = fma((double)c0.y, (double)c0.y, n2d);
    n2d = fma((double)c0.z, (double)c0.z, n2d); n2d = fma((double)c0.w, (double)c0.w, n2d);
    n2d = fma((double)c1.x, (double)c1.x, n2d); n2d = fma((double)c1.y, (double)c1.y, n2d);
    n2d = fma((double)c1.z, (double)c1.z, n2d); n2d = fma((double)c1.w, (double)c1.w, n2d);

    // --- row absmax reduction ---
    float m = 0.f;
#pragma unroll
    for (int i = 0; i < 16; ++i) m = fmaxf(m, fabsf(w[i]));
#pragma unroll
    for (int off = 32; off > 0; off >>= 1)
        m = fmaxf(m, __shfl_down(m, off, 64));
    int wave = t >> 6, lane = t & 63;
    if (lane == 0) red[wave] = m;
    __syncthreads();   // also covers cb[] writes
    float s = fmaxf(fmaxf(fmaxf(red[0], red[1]), fmaxf(red[2], red[3])), 1e-6f);
    sn[t] = (float)((double)s * n2d);   // single rounding
    __syncthreads();

    // --- fp32 search, best + second-best ---
    float best0 = 1e30f, sec0 = 1e30f, best1 = 1e30f, sec1 = 1e30f;
    int bi0 = 0, bi1 = 0;
    for (int c = 0; c < KCB; ++c) {
        float4 p0 = *(const float4*)&cb[c * PQD];
        float4 p1 = *(const float4*)&cb[c * PQD + 4];
        float snc = sn[c];
        float d0 = 0.f, d1 = 0.f;
        d0 = fmaf(p0.x, w[0], d0);  d0 = fmaf(p0.y, w[1], d0);
        d0 = fmaf(p0.z, w[2], d0);  d0 = fmaf(p0.w, w[3], d0);
        d0 = fmaf(p1.x, w[4], d0);  d0 = fmaf(p1.y, w[5], d0);
        d0 = fmaf(p1.z, w[6], d0);  d0 = fmaf(p1.w, w[7], d0);
        d1 = fmaf(p0.x, w[8], d1);  d1 = fmaf(p0.y, w[9], d1);
        d1 = fmaf(p0.z, w[10], d1); d1 = fmaf(p0.w, w[11], d1);
        d1 = fmaf(p1.x, w[12], d1); d1 = fmaf(p1.y, w[13], d1);
        d1 = fmaf(p1.z, w[14], d1); d1 = fmaf(p1.w, w[15], d1);
        float e0 = fmaf(-2.f, d0, snc);
        float e1 = fmaf(-2.f, d1, snc);
        bool lt0 = e0 < best0;
        sec0 = fminf(sec0, lt0 ? best0 : e0);
        best0 = fminf(best0, e0);
        bi0 = lt0 ? c : bi0;
        bool lt1 = e1 < best1;
        sec1 = fminf(sec1, lt1 ? best1 : e1);
        best1 = fminf(best1, e1);
        bi1 = lt1 ? c : bi1;
    }

    // --- cheap exact fallback: fp32 re-loop, fp64 only for near-best candidates ---
    if (sec0 - best0 < TAU) {
        double sd = (double)s;
        double g[PQD];
#pragma unroll
        for (int d = 0; d < PQD; ++d) g[d] = (double)w[d] / sd;
        double bb = 1e300; int bi = 0;
        float cut = best0 + CUT;
        for (int c = 0; c < KCB; ++c) {
            float4 p0 = *(const float4*)&cb[c * PQD];
            float4 p1 = *(const float4*)&cb[c * PQD + 4];
            float d0 = 0.f;
            d0 = fmaf(p0.x, w[0], d0);  d0 = fmaf(p0.y, w[1], d0);
            d0 = fmaf(p0.z, w[2], d0);  d0 = fmaf(p0.w, w[3], d0);
            d0 = fmaf(p1.x, w[4], d0);  d0 = fmaf(p1.y, w[5], d0);
            d0 = fmaf(p1.z, w[6], d0);  d0 = fmaf(p1.w, w[7], d0);
            float e0 = fmaf(-2.f, d0, sn[c]);
            if (e0 <= cut) {
                double n = 0.0, dot = 0.0;
#pragma unroll
                for (int d = 0; d < PQD; ++d) {
                    double cv = (double)cb[c * PQD + d];
                    n = fma(cv, cv, n);
                    dot = fma(cv, g[d], dot);
                }
                double d2 = fma(-2.0, dot, n);
                if (d2 < bb) { bb = d2; bi = c; }
            }
        }
        bi0 = bi;
    }
    if (sec1 - best1 < TAU) {
        double sd = (double)s;
        double g[PQD];
#pragma unroll
        for (int d = 0; d < PQD; ++d) g[d] = (double)w[8 + d] / sd;
        double bb = 1e300; int bi = 0;
        float cut = best1 + CUT;
        for (int c = 0; c < KCB; ++c) {
            float4 p0 = *(const float4*)&cb[c * PQD];
            float4 p1 = *(const float4*)&cb[c * PQD + 4];
            float d1 = 0.f;
            d1 = fmaf(p0.x, w[8], d1);  d1 = fmaf(p0.y, w[9], d1);
            d1 = fmaf(p0.z, w[10], d1); d1 = fmaf(p0.w, w[11], d1);
            d1 = fmaf(p1.x, w[12], d1); d1 = fmaf(p1.y, w[13], d1);
            d1 = fmaf(p1.z, w[14], d1); d1 = fmaf(p1.w, w[15], d1);
            float e1 = fmaf(-2.f, d1, sn[c]);
            if (e1 <= cut) {
                double n = 0.0, dot = 0.0;
#pragma unroll
                for (int d = 0; d < PQD; ++d) {
                    double cv = (double)cb[c * PQD + d];
                    n = fma(cv, cv, n);
                    dot = fma(cv, g[d], dot);
                }
                double d2 = fma(-2.0, dot, n);
                if (d2 < bb) { bb = d2; bi = c; }
            }
        }
        bi1 = bi;
    }

    // --- dequantize to bf16 (rescaled) ---
    unsigned short u[16];
#pragma unroll
    for (int d = 0; d < PQD; ++d) u[d]     = f32_to_bf16(cb[bi0 * PQD + d] * s);
#pragma unroll
    for (int d = 0; d < PQD; ++d) u[8 + d] = f32_to_bf16(cb[bi1 * PQD + d] * s);
    uint4 r0, r1;
    r0.x = pack2(u[0], u[1]);   r0.y = pack2(u[2], u[3]);
    r0.z = pack2(u[4], u[5]);   r0.w = pack2(u[6], u[7]);
    r1.x = pack2(u[8], u[9]);   r1.y = pack2(u[10], u[11]);
    r1.z = pack2(u[12], u[13]); r1.w = pack2(u[14], u[15]);
    unsigned short* dst = wq + (size_t)o * I_DIM + t * 16;
    *(uint4*)(dst)     = r0;
    *(uint4*)(dst + 8) = r1;
}

// ---------------- 2. bf16 MFMA GEMM, A read as fp32 (in-flight cvt) + bias ----------------
// A staged fp32 via global_load_lds with XOR seg-swizzle (seg' = seg ^ (row&7))
// so fp32 frag reads stay at the conflict-free b128 8-phase floor. Only the
// per-lane GLOBAL source changes (LDS dest is the HW's lane-ordered layout).
#define TM 128
#define TN 128
#define BK 32

__global__ __launch_bounds__(256) void gemm_af32_bias(const float* __restrict__ A,          // [BS_TOK][I] fp32
                                                      const unsigned short* __restrict__ B, // [O_DIM][I] bf16
                                                      const float* __restrict__ bias,
                                                      float* __restrict__ C) {
    __shared__ __align__(16) float lds_a[TM * BK];          // 16 KB (seg-swizzled)
    __shared__ __align__(16) unsigned short lds_b[TN * BK]; // 8 KB

    const int t = threadIdx.x;
    const int wave = t >> 6;
    const int lane = t & 63;
    const int quad = lane >> 4;
    const int lr = lane & 15;

    // XCD-contiguous swizzle (round-2 verified: FETCH 279->165 MB)
    int lid = blockIdx.y * gridDim.x + blockIdx.x;          // 0..1023
    int nlid = (lid >> 3) + (lid & 7) * 128;
    const int bm = (nlid >> 4) * TM;
    const int bn = (nlid & 15) * TN;

    const int wm = (wave >> 1) * 64;
    const int wn = (wave & 1) * 64;

    // staging lane decomposition
    const int ar_ = lane >> 3, as_ = lane & 7;   // A chunk: 8 rows x 8 fp32-segs (16B)
    const int br_ = lane >> 2, bs_ = lane & 3;   // B chunk: 16 rows x 4 bf16-segs (16B)

    f32x4 acc[4][4] = {};

    for (int k0 = 0; k0 < I_DIM; k0 += BK) {
#pragma unroll
        for (int cc = 0; cc < 6; ++cc) {
            int cid = wave + cc * 4;              // 0..23, wave-uniform
            if (cid < 16) {                       // A: 16 chunks of 8 rows (fp32)
                int row = bm + cid * 8 + ar_;
                const float* gsrc = A + (size_t)row * I_DIM + k0 + ((as_ ^ ar_) << 2);
                float* ldst = lds_a + cid * 256;  // HW adds lane*16B
                __builtin_amdgcn_global_load_lds((const __attribute__((address_space(1))) void*)gsrc,
                                                 (__attribute__((address_space(3))) void*)ldst,
                                                 16, 0, 0);
            } else {                              // B: 8 chunks of 16 rows (bf16)
                int b = cid - 16;
                int row = bn + b * 16 + br_;
                const unsigned short* gsrc = B + (size_t)row * I_DIM + k0 + bs_ * 8;
                unsigned short* ldst = lds_b + b * 512;
                __builtin_amdgcn_global_load_lds((const __attribute__((address_space(1))) void*)gsrc,
                                                 (__attribute__((address_space(3))) void*)ldst,
                                                 16, 0, 0);
            }
        }
        __syncthreads();

        bf16x8 af[4], bfr[4];
#pragma unroll
        for (int i = 0; i < 4; ++i) {
            int mrow = wm + i * 16 + lr;
            const float* ap = lds_a + mrow * 32;
            int sw = mrow & 7;
            float4 lo = *(const float4*)(ap + (((2 * quad) ^ sw) << 2));
            float4 hi = *(const float4*)(ap + (((2 * quad + 1) ^ sw) << 2));
            bf16x8 v;
            v[0] = (__bf16)lo.x; v[1] = (__bf16)lo.y; v[2] = (__bf16)lo.z; v[3] = (__bf16)lo.w;
            v[4] = (__bf16)hi.x; v[5] = (__bf16)hi.y; v[6] = (__bf16)hi.z; v[7] = (__bf16)hi.w;
            af[i] = v;
        }
#pragma unroll
        for (int j = 0; j < 4; ++j)
            bfr[j] = *(const bf16x8*)&lds_b[(wn + j * 16 + lr) * BK + quad * 8];
#pragma unroll
        for (int i = 0; i < 4; ++i)
#pragma unroll
            for (int j = 0; j < 4; ++j)
                acc[i][j] = __builtin_amdgcn_mfma_f32_16x16x32_bf16(af[i], bfr[j], acc[i][j], 0, 0, 0);
        __syncthreads();
    }

#pragma unroll
    for (int i = 0; i < 4; ++i) {
        int mrow_base = bm + wm + i * 16 + quad * 4;
#pragma unroll
        for (int j = 0; j < 4; ++j) {
            int n = bn + wn + j * 16 + lr;
            float bv = bias[n];
#pragma unroll
            for (int r = 0; r < 4; ++r) {
                int m = mrow_base + r;
                C[(size_t)m * O_DIM + n] = acc[i][j][r] + bv;
            }
        }
    }
}

extern "C" void kernel_launch(void* const* d_in, const int* in_sizes, int n_in,
                              void* d_out, int out_size, void* d_ws, size_t ws_size,
                              hipStream_t stream) {
    const float* x        = (const float*)d_in[0];
    const float* weight   = (const float*)d_in[1];
    const float* codebook = (const float*)d_in[2];
    const float* bias     = (const float*)d_in[3];
    float* out = (float*)d_out;

    unsigned short* wq = (unsigned short*)d_ws;   // 16 MB bf16 dequantized weight

    fused_assign_kernel<<<O_DIM, 256, 0, stream>>>(weight, codebook, wq);
    gemm_af32_bias<<<dim3(O_DIM / TN, BS_TOK / TM), 256, 0, stream>>>(x, wq, bias, out);
}

// Round 4
// 501.472 us; speedup vs baseline: 1.1953x; 1.1953x over previous
//
#include <hip/hip_runtime.h>
#include <stdint.h>

#define O_DIM 2048
#define I_DIM 4096
#define BS_TOK 8192   // 4*2048 tokens
#define KCB 256
#define PQD 8

typedef __attribute__((ext_vector_type(8))) __bf16 bf16x8;
typedef __attribute__((ext_vector_type(4))) float f32x4;

static __device__ __forceinline__ unsigned short f32_to_bf16(float f) {
    unsigned int u = __float_as_uint(f);
    u += 0x7fffu + ((u >> 16) & 1u);   // round-to-nearest-even
    return (unsigned short)(u >> 16);
}

static __device__ __forceinline__ unsigned int pack2(unsigned short lo, unsigned short hi) {
    return (unsigned int)lo | ((unsigned int)hi << 16);
}

// ---------------- 1. fused rowscale + assignment, 4 groups/thread ----------------
// e(c) = -2*(w.c) + s*||c||^2 : same argmin as ||w/s - c||^2 (scale by s>0).
// fp32 search tracks best+second per slot; flagged slots (margin < TAU) rerun
// with fp64 evaluation of candidates within CUT of best (ascending c =
// np.argmin first-min tiebreak; fp64 formula identical to round-1-verified).
// TAU/CUT sized for worst-case fp32 error ~7e-5 (two-rounding s*n2 path).
#define TAU 1.5e-4f
#define CUT 3.0e-4f

__global__ __launch_bounds__(256) void fused_assign_kernel(const float* __restrict__ weight,
                                                           const float* __restrict__ codebook,
                                                           unsigned short* __restrict__ wq) {
    __shared__ __align__(16) float cb[KCB * PQD];   // 8 KB
    __shared__ float n2[KCB];                       // 1 KB  (fl32 of fp64 ||c||^2)
    __shared__ float red[4];

    const int t = threadIdx.x;
    const int half = t >> 7;            // 0: row0, 1: row1
    const int tid = t & 127;            // position within row
    const int o = blockIdx.x * 2 + half;

    // --- load my 32 weights (4 groups) ---
    const float* wp = weight + (size_t)o * I_DIM + tid * 32;
    float w[32];
#pragma unroll
    for (int q = 0; q < 8; ++q) {
        float4 v = *(const float4*)(wp + q * 4);
        w[q * 4 + 0] = v.x; w[q * 4 + 1] = v.y; w[q * 4 + 2] = v.z; w[q * 4 + 3] = v.w;
    }

    // --- my codeword -> LDS; exact norm via fp64 ---
    float4 c0 = *(const float4*)(codebook + t * PQD);
    float4 c1 = *(const float4*)(codebook + t * PQD + 4);
    *(float4*)&cb[t * PQD]     = c0;
    *(float4*)&cb[t * PQD + 4] = c1;
    double n2d = 0.0;
    n2d = fma((double)c0.x, (double)c0.x, n2d); n2d = fma((double)c0.y, (double)c0.y, n2d);
    n2d = fma((double)c0.z, (double)c0.z, n2d); n2d = fma((double)c0.w, (double)c0.w, n2d);
    n2d = fma((double)c1.x, (double)c1.x, n2d); n2d = fma((double)c1.y, (double)c1.y, n2d);
    n2d = fma((double)c1.z, (double)c1.z, n2d); n2d = fma((double)c1.w, (double)c1.w, n2d);
    n2[t] = (float)n2d;

    // --- per-row absmax: waves 0,1 cover row0; waves 2,3 cover row1 ---
    float m = 0.f;
#pragma unroll
    for (int i = 0; i < 32; ++i) m = fmaxf(m, fabsf(w[i]));
#pragma unroll
    for (int off = 32; off > 0; off >>= 1)
        m = fmaxf(m, __shfl_down(m, off, 64));
    int wave = t >> 6, lane = t & 63;
    if (lane == 0) red[wave] = m;
    __syncthreads();   // also covers cb[]/n2[] writes
    float s = fmaxf(fmaxf(red[half * 2], red[half * 2 + 1]), 1e-6f);

    // --- fp32 search, best + second per slot ---
    float best[4] = {1e30f, 1e30f, 1e30f, 1e30f};
    float sec[4]  = {1e30f, 1e30f, 1e30f, 1e30f};
    int bi[4] = {0, 0, 0, 0};
#pragma unroll 2
    for (int c = 0; c < KCB; ++c) {
        float4 p0 = *(const float4*)&cb[c * PQD];
        float4 p1 = *(const float4*)&cb[c * PQD + 4];
        float t1 = s * n2[c];
#pragma unroll
        for (int k = 0; k < 4; ++k) {
            const float* wk = w + k * 8;
            float d = 0.f;
            d = fmaf(p0.x, wk[0], d); d = fmaf(p0.y, wk[1], d);
            d = fmaf(p0.z, wk[2], d); d = fmaf(p0.w, wk[3], d);
            d = fmaf(p1.x, wk[4], d); d = fmaf(p1.y, wk[5], d);
            d = fmaf(p1.z, wk[6], d); d = fmaf(p1.w, wk[7], d);
            float e = fmaf(-2.f, d, t1);
            bool lt = e < best[k];
            sec[k] = fminf(sec[k], lt ? best[k] : e);
            best[k] = fminf(best[k], e);
            bi[k] = lt ? c : bi[k];
        }
    }

    // --- rare exact fallback per slot ---
#pragma unroll
    for (int k = 0; k < 4; ++k) {
        if (sec[k] - best[k] < TAU) {
            const float* wk = w + k * 8;
            double sd = (double)s;
            double g[PQD];
#pragma unroll
            for (int d = 0; d < PQD; ++d) g[d] = (double)wk[d] / sd;
            double bb = 1e300; int bbi = 0;
            float cut = best[k] + CUT;
            for (int c = 0; c < KCB; ++c) {
                float4 p0 = *(const float4*)&cb[c * PQD];
                float4 p1 = *(const float4*)&cb[c * PQD + 4];
                float d0 = 0.f;
                d0 = fmaf(p0.x, wk[0], d0); d0 = fmaf(p0.y, wk[1], d0);
                d0 = fmaf(p0.z, wk[2], d0); d0 = fmaf(p0.w, wk[3], d0);
                d0 = fmaf(p1.x, wk[4], d0); d0 = fmaf(p1.y, wk[5], d0);
                d0 = fmaf(p1.z, wk[6], d0); d0 = fmaf(p1.w, wk[7], d0);
                float e0 = fmaf(-2.f, d0, s * n2[c]);
                if (e0 <= cut) {
                    double n = 0.0, dot = 0.0;
#pragma unroll
                    for (int d = 0; d < PQD; ++d) {
                        double cv = (double)cb[c * PQD + d];
                        n = fma(cv, cv, n);
                        dot = fma(cv, g[d], dot);
                    }
                    double d2 = fma(-2.0, dot, n);
                    if (d2 < bb) { bb = d2; bbi = c; }
                }
            }
            bi[k] = bbi;
        }
    }

    // --- dequantize to bf16 (rescaled), 64 B contiguous per thread ---
    unsigned short* dst = wq + (size_t)o * I_DIM + tid * 32;
#pragma unroll
    for (int k = 0; k < 4; ++k) {
        unsigned short u[8];
#pragma unroll
        for (int d = 0; d < PQD; ++d) u[d] = f32_to_bf16(cb[bi[k] * PQD + d] * s);
        uint4 r;
        r.x = pack2(u[0], u[1]); r.y = pack2(u[2], u[3]);
        r.z = pack2(u[4], u[5]); r.w = pack2(u[6], u[7]);
        *(uint4*)(dst + k * 8) = r;
    }
}

// ---------------- 2. x fp32 -> bf16 ----------------
__global__ __launch_bounds__(256) void convert_kernel(const float* __restrict__ x,
                                                      unsigned short* __restrict__ xb) {
    size_t i = ((size_t)blockIdx.x * 256 + threadIdx.x) * 8;
    float4 v0 = *(const float4*)(x + i);
    float4 v1 = *(const float4*)(x + i + 4);
    uint4 r;
    r.x = pack2(f32_to_bf16(v0.x), f32_to_bf16(v0.y));
    r.y = pack2(f32_to_bf16(v0.z), f32_to_bf16(v0.w));
    r.z = pack2(f32_to_bf16(v1.x), f32_to_bf16(v1.y));
    r.w = pack2(f32_to_bf16(v1.z), f32_to_bf16(v1.w));
    *(uint4*)(xb + i) = r;
}

// ---------------- 3. bf16 MFMA GEMM (B^T layout) + bias — round-2 verified (198 us) ----------------
#define TM 128
#define TN 128
#define BK 32

__global__ __launch_bounds__(256) void gemm_bt_bias(const unsigned short* __restrict__ A, // [BS_TOK][I]
                                                    const unsigned short* __restrict__ B, // [O_DIM][I]
                                                    const float* __restrict__ bias,
                                                    float* __restrict__ C) {
    __shared__ __align__(16) unsigned short lds_a[TM * BK]; // 8 KB
    __shared__ __align__(16) unsigned short lds_b[TN * BK]; // 8 KB

    const int t = threadIdx.x;
    const int wave = t >> 6;
    const int lane = t & 63;
    const int quad = lane >> 4;
    const int lr = lane & 15;

    // XCD-contiguous swizzle (round-2 verified: FETCH 279->165 MB)
    int lid = blockIdx.y * gridDim.x + blockIdx.x;          // 0..1023
    int nlid = (lid >> 3) + (lid & 7) * 128;
    const int bm = (nlid >> 4) * TM;
    const int bn = (nlid & 15) * TN;

    const int wm = (wave >> 1) * 64;
    const int wn = (wave & 1) * 64;
    const int sub_row = lane >> 2;  // 0..15 within a 16-row chunk
    const int seg = lane & 3;       // 16B segment within a 64B row

    f32x4 acc[4][4] = {};

    for (int k0 = 0; k0 < I_DIM; k0 += BK) {
#pragma unroll
        for (int cc = 0; cc < 4; ++cc) {
            int cid = wave + cc * 4;              // 0..15, wave-uniform
            const unsigned short* gsrc;
            unsigned short* ldst;
            if (cid < 8) {
                int row = bm + cid * 16 + sub_row;
                gsrc = A + (size_t)row * I_DIM + k0 + seg * 8;
                ldst = lds_a + cid * 512;
            } else {
                int row = bn + (cid - 8) * 16 + sub_row;
                gsrc = B + (size_t)row * I_DIM + k0 + seg * 8;
                ldst = lds_b + (cid - 8) * 512;
            }
            __builtin_amdgcn_global_load_lds((const __attribute__((address_space(1))) void*)gsrc,
                                             (__attribute__((address_space(3))) void*)ldst,
                                             16, 0, 0);
        }
        __syncthreads();

        bf16x8 af[4], bfr[4];
#pragma unroll
        for (int i = 0; i < 4; ++i)
            af[i] = *(const bf16x8*)&lds_a[(wm + i * 16 + lr) * BK + quad * 8];
#pragma unroll
        for (int j = 0; j < 4; ++j)
            bfr[j] = *(const bf16x8*)&lds_b[(wn + j * 16 + lr) * BK + quad * 8];
#pragma unroll
        for (int i = 0; i < 4; ++i)
#pragma unroll
            for (int j = 0; j < 4; ++j)
                acc[i][j] = __builtin_amdgcn_mfma_f32_16x16x32_bf16(af[i], bfr[j], acc[i][j], 0, 0, 0);
        __syncthreads();
    }

#pragma unroll
    for (int i = 0; i < 4; ++i) {
        int mrow_base = bm + wm + i * 16 + quad * 4;
#pragma unroll
        for (int j = 0; j < 4; ++j) {
            int n = bn + wn + j * 16 + lr;
            float bv = bias[n];
#pragma unroll
            for (int r = 0; r < 4; ++r) {
                int m = mrow_base + r;
                C[(size_t)m * O_DIM + n] = acc[i][j][r] + bv;
            }
        }
    }
}

extern "C" void kernel_launch(void* const* d_in, const int* in_sizes, int n_in,
                              void* d_out, int out_size, void* d_ws, size_t ws_size,
                              hipStream_t stream) {
    const float* x        = (const float*)d_in[0];
    const float* weight   = (const float*)d_in[1];
    const float* codebook = (const float*)d_in[2];
    const float* bias     = (const float*)d_in[3];
    float* out = (float*)d_out;

    char* ws = (char*)d_ws;
    unsigned short* wq = (unsigned short*)ws;                               // 16 MB
    unsigned short* xb = (unsigned short*)(ws + (size_t)O_DIM * I_DIM * 2); // 64 MB

    fused_assign_kernel<<<O_DIM / 2, 256, 0, stream>>>(weight, codebook, wq);
    convert_kernel<<<((size_t)BS_TOK * I_DIM / 8) / 256, 256, 0, stream>>>(x, xb);
    gemm_bt_bias<<<dim3(O_DIM / TN, BS_TOK / TM), 256, 0, stream>>>(xb, wq, bias, out);
}